// Round 1
// 174.256 us; speedup vs baseline: 1.0022x; 1.0022x over previous
//
#include <hip/hip_runtime.h>
#include <math.h>

#define B 4
#define CIN 64
#define H 128
#define W 128
#define COUT 128
#define KK 9
#define HW (H*W)

#define OFFS_SZ (B*18*HW)
#define MASK_SZ (B*9*HW)
#define WTAP_SZ (CIN*KK*32)
#define WBF_COLS 640                 // 4 chunks x 160 (144 real + 16 zero)
#define WBF_SHORTS (COUT*WBF_COLS)
#define LDK 168                      // LDS k-stride (shorts); 336B row stride

typedef __attribute__((ext_vector_type(8))) short short8;
typedef __attribute__((ext_vector_type(4))) float f32x4;
typedef __attribute__((ext_vector_type(2))) float f32x2;
typedef f32x2 __attribute__((aligned(4))) f32x2a;   // align-4 float2 load

__device__ __forceinline__ unsigned short f2bf(float f) {
    unsigned int u = __float_as_uint(f);
    u += 0x7fffu + ((u >> 16) & 1u);
    return (unsigned short)(u >> 16);
}

// ---------------------------------------------------------------------------
// prep: wtap[(c*9+tap)*32+f] (offmask weights, f padded to 32), bcat biases
// ---------------------------------------------------------------------------
__global__ void prep_kernel(const float* __restrict__ w_off, const float* __restrict__ b_off,
                            const float* __restrict__ w_mask, const float* __restrict__ b_mask,
                            float* __restrict__ wtap, float* __restrict__ bcat)
{
    int idx = blockIdx.x * 256 + threadIdx.x;
    if (idx < WTAP_SZ) {
        int f = idx & 31;
        int tap = (idx >> 5) % 9;
        int c = idx / (32 * 9);
        float v = 0.f;
        if (f < 18) v = w_off[(f * CIN + c) * 9 + tap];
        else if (f < 27) v = w_mask[((f - 18) * CIN + c) * 9 + tap];
        wtap[idx] = v;
    }
    if (blockIdx.x == 0 && threadIdx.x < 32) {
        int f = threadIdx.x;
        float bv = 0.f;
        if (f < 18) bv = b_off[f];
        else if (f < 27) bv = b_mask[f - 18];
        bcat[f] = bv;
    }
}

// ---------------------------------------------------------------------------
// prep_wbf: einsum weights -> bf16, layout [o][cb*160 + tap*16 + ci];
// pad cols [144,160) per chunk are ZERO.
// ---------------------------------------------------------------------------
__global__ void prep_wbf(const float* __restrict__ wgt, short* __restrict__ wbf)
{
    int idx = blockIdx.x * 256 + threadIdx.x;
    if (idx >= WBF_SHORTS) return;
    int o  = idx / WBF_COLS;
    int kp = idx % WBF_COLS;
    int cb = kp / 160, r = kp % 160;
    float v = 0.f;
    if (r < 144) {
        int tap = r >> 4;
        int c   = cb * 16 + (r & 15);
        v = wgt[(o * CIN + c) * KK + tap];
    }
    wbf[idx] = (short)f2bf(v);
}

// ---------------------------------------------------------------------------
// offmask: 27-filter 3x3 conv. Block = 64 px (32 f x 8 pg of 8 px).
// Grid (2, H, B) = 1024 -> 4 blocks/CU.
// Change this round: wtap chunk weights staged in LDS (coalesced, 9x256
// floats exactly) instead of 9 serial dependent global loads per channel.
// ---------------------------------------------------------------------------
#define CC 8
__global__ __launch_bounds__(256) void offmask_kernel(
    const float* __restrict__ x, const float* __restrict__ wtap,
    const float* __restrict__ bcat, float* __restrict__ offs,
    float* __restrict__ mask)
{
    const int wo0 = blockIdx.x * 64;
    const int ho  = blockIdx.y;
    const int b   = blockIdx.z;
    const int tid = threadIdx.x;
    const int f   = tid & 31;
    const int pg  = tid >> 5;
    const int px0 = pg * 8;

    __shared__ float lx[CC * 3 * 72];    // 6,912 B
    __shared__ float lw[CC * 9 * 32];    // 9,216 B  (chunk weights)

    float acc[8];
    #pragma unroll
    for (int i = 0; i < 8; ++i) acc[i] = 0.f;

    const float* xb = x + b * CIN * HW;

    for (int cb = 0; cb < CIN; cb += CC) {
        if (cb) __syncthreads();
        #pragma unroll
        for (int i = 0; i < 7; ++i) {
            int idx = tid + i * 256;
            if (idx < CC * 3 * 72) {
                int c  = idx / 216;
                int rem = idx % 216;
                int ry = rem / 72;
                int j  = rem % 72;
                int g  = wo0 - 2 + j;
                int y  = ho - 1 + ry;
                float v = (y >= 0 && y < H && g >= 0 && g < W)
                          ? xb[(cb + c) * HW + y * W + g] : 0.f;
                lx[idx] = v;
            }
        }
        // wtap slice for this chunk is contiguous: 2304 floats = 9*256
        #pragma unroll
        for (int i = 0; i < 9; ++i) {
            int idx = tid + i * 256;
            lw[idx] = wtap[cb * (9 * 32) + idx];
        }
        __syncthreads();
        #pragma unroll 1
        for (int c = 0; c < CC; ++c) {
            float wv[9];
            #pragma unroll
            for (int t = 0; t < 9; ++t)
                wv[t] = lw[(c * 9 + t) * 32 + f];
            float xr[3][10];
            #pragma unroll
            for (int q = 0; q < 3; ++q) {
                #pragma unroll
                for (int t = 0; t < 10; ++t)
                    xr[q][t] = lx[(c * 3 + q) * 72 + px0 + 1 + t];
            }
            #pragma unroll
            for (int ky = 0; ky < 3; ++ky) {
                #pragma unroll
                for (int kx = 0; kx < 3; ++kx) {
                    float w = wv[ky * 3 + kx];
                    #pragma unroll
                    for (int p = 0; p < 8; ++p)
                        acc[p] += xr[ky][p + kx] * w;
                }
            }
        }
    }

    const float bv = bcat[f];
    if (f < 18) {
        float* op = offs + ((b * 18 + f) * H + ho) * W + wo0 + px0;
        #pragma unroll
        for (int p = 0; p < 8; ++p) op[p] = acc[p] + bv;
    } else if (f < 27) {
        float* mp = mask + ((b * 9 + (f - 18)) * H + ho) * W + wo0 + px0;
        #pragma unroll
        for (int p = 0; p < 8; ++p) {
            float a = acc[p] + bv;
            mp[p] = 1.f / (1.f + expf(-a));
        }
    }
}

// ---------------------------------------------------------------------------
// deform2: fused bilinear-sample + MFMA einsum.
// Block = 256 thr = 4 waves; tile 64 px x 128 out; grid (2, H, B) = 1024.
// Change this round: gather loads issued as explicit 16-load batches
// (register arrays) BEFORE the convert/pack loop -> 16-deep MLP instead of
// serial load->waitcnt->use chains (the 650 cy/load stall seen in rocprof).
// ---------------------------------------------------------------------------
__global__ __launch_bounds__(256, 4) void deform2_kernel(
    const float* __restrict__ x, const float* __restrict__ offs,
    const float* __restrict__ maskp, const short* __restrict__ wbf,
    float* __restrict__ out)
{
    const int half = blockIdx.x;          // px half of the row
    const int ho   = blockIdx.y;
    const int b    = blockIdx.z;
    const int wo0  = half * 64;
    const int tid  = threadIdx.x;
    const int lane = tid & 63;
    const int wv   = tid >> 6;
    const int oh   = (wv & 1) * 64;
    const int ph   = (wv >> 1) * 32;
    const int row16 = lane & 15, kq = lane >> 4;

    __shared__ __align__(16) short S[64 * LDK];   // 21,504 B

    if (tid < 128) {                      // zero K-pad [144,160) once
        short8 z = {0,0,0,0,0,0,0,0};
        *(short8*)&S[(tid >> 1) * LDK + 144 + (tid & 1) * 8] = z;
    }

    // ---- metadata: slot s = tid + j*256 -> (tap k = s>>6, px p = s&63) ----
    int   moff[3][2];
    float wA0[3], wB0[3], wA1[3], wB1[3];
    #pragma unroll
    for (int j = 0; j < 3; ++j) {
        moff[j][0] = 0; moff[j][1] = 0;
        wA0[j] = 0.f; wB0[j] = 0.f; wA1[j] = 0.f; wB1[j] = 0.f;
        int s = tid + j * 256;
        if (s < 576) {
            int k = s >> 6, p = s & 63;
            int wo = wo0 + p;
            int ky = k / 3, kx = k % 3;
            int obase = ((b * 18 + 2 * k) * H + ho) * W + wo;
            float dy = offs[obase];
            float dx = offs[obase + HW];
            float mk = maskp[((b * 9 + k) * H + ho) * W + wo];
            float py  = (float)(ho - 1 + ky) + dy;
            float pxf = (float)(wo - 1 + kx) + dx;
            float fy = floorf(py), fx = floorf(pxf);
            float ly = py - fy, lx = pxf - fx;
            int y0 = (int)fy, x0 = (int)fx;
            int y1 = y0 + 1,  x1 = x0 + 1;
            bool vy0 = (y0 >= 0) && (y0 < H);
            bool vy1 = (y1 >= 0) && (y1 < H);
            bool vx0 = (x0 >= 0) && (x0 < W);
            bool vx1 = (x1 >= 0) && (x1 < W);
            float w0 = (vy0 && vx0) ? (1.f - ly) * (1.f - lx) * mk : 0.f;
            float w1 = (vy0 && vx1) ? (1.f - ly) * lx * mk : 0.f;
            float w2 = (vy1 && vx0) ? ly * (1.f - lx) * mk : 0.f;
            float w3 = (vy1 && vx1) ? ly * lx * mk : 0.f;
            int lc = min(max(x0, 0), W - 2);
            bool sel = (x0 == lc);
            int r0 = min(max(y0, 0), H - 1);
            int r1 = min(max(y1, 0), H - 1);
            moff[j][0] = (r0 * W + lc) * 4;
            moff[j][1] = (r1 * W + lc) * 4;
            wA0[j] = sel ? w0 : w1;  wB0[j] = sel ? w1 : w0;
            wA1[j] = sel ? w2 : w3;  wB1[j] = sel ? w3 : w2;
        }
    }

    f32x4 acc[4][2];
    #pragma unroll
    for (int i = 0; i < 4; ++i)
        #pragma unroll
        for (int j = 0; j < 2; ++j)
            acc[i][j] = (f32x4){0.f, 0.f, 0.f, 0.f};

    const char* xbc = (const char*)(x + b * CIN * HW);

    #pragma unroll 1
    for (int cb = 0; cb < 4; ++cb) {
        // ---- gather 16 channels into S: per slot, per 8-ch half:
        //      issue all 16 corner-pair loads into register arrays first,
        //      THEN convert -> bf16 and ds_write. This gives 16-deep MLP.
        #pragma unroll
        for (int j = 0; j < 3; ++j) {
            int s = tid + j * 256;
            if (s < 576) {
                int k = s >> 6, p = s & 63;
                #pragma unroll
                for (int h2 = 0; h2 < 2; ++h2) {
                    const char* pcb = xbc + (size_t)(cb * 16 + h2 * 8) * (HW * 4);
                    f32x2 ra[8], rb[8];
                    #pragma unroll
                    for (int ci = 0; ci < 8; ++ci) {
                        const char* pc = pcb + (size_t)ci * (HW * 4);
                        ra[ci] = *(const f32x2a*)(pc + moff[j][0]);
                        rb[ci] = *(const f32x2a*)(pc + moff[j][1]);
                    }
                    short8 s8;
                    #pragma unroll
                    for (int ci = 0; ci < 8; ++ci) {
                        float v = wA0[j] * ra[ci].x + wB0[j] * ra[ci].y
                                + wA1[j] * rb[ci].x + wB1[j] * rb[ci].y;
                        s8[ci] = (short)f2bf(v);
                    }
                    *(short8*)&S[p * LDK + k * 16 + h2 * 8] = s8;
                }
            }
        }
        __syncthreads();
        // ---- MFMA: K=160 (5 steps of 32) ----
        #pragma unroll
        for (int ks = 0; ks < 5; ++ks) {
            short8 a[4];
            #pragma unroll
            for (int of = 0; of < 4; ++of) {
                int o = oh + of * 16 + row16;
                a[of] = *(const short8*)(wbf + o * WBF_COLS + cb * 160 + ks * 32 + kq * 8);
            }
            #pragma unroll
            for (int pf = 0; pf < 2; ++pf) {
                int p = ph + pf * 16 + row16;
                short8 bfr = *(const short8*)&S[p * LDK + ks * 32 + kq * 8];
                #pragma unroll
                for (int of = 0; of < 4; ++of)
                    acc[of][pf] = __builtin_amdgcn_mfma_f32_16x16x32_bf16(
                        a[of], bfr, acc[of][pf], 0, 0, 0);
            }
        }
        __syncthreads();
    }

    // ---- store: C/D layout col(px)=lane&15, row(o)=(lane>>4)*4+r ----
    #pragma unroll
    for (int of = 0; of < 4; ++of) {
        #pragma unroll
        for (int r = 0; r < 4; ++r) {
            int o = oh + of * 16 + kq * 4 + r;
            float* orow = out + ((b * COUT + o) * H + ho) * W;
            #pragma unroll
            for (int pf = 0; pf < 2; ++pf) {
                int wo = wo0 + ph + pf * 16 + row16;
                orow[wo] = acc[of][pf][r];
            }
        }
    }
}

// ---------------------------------------------------------------------------
extern "C" void kernel_launch(void* const* d_in, const int* in_sizes, int n_in,
                              void* d_out, int out_size, void* d_ws, size_t ws_size,
                              hipStream_t stream)
{
    const float* x      = (const float*)d_in[0];
    const float* w_off  = (const float*)d_in[1];
    const float* b_off  = (const float*)d_in[2];
    const float* w_mask = (const float*)d_in[3];
    const float* b_mask = (const float*)d_in[4];
    const float* weight = (const float*)d_in[5];
    float* out   = (float*)d_out;
    float* offs  = (float*)d_ws;
    float* maskb = offs + OFFS_SZ;
    float* wtap  = maskb + MASK_SZ;
    float* bcat  = wtap + WTAP_SZ;
    short* wbf   = (short*)(bcat + 32);

    prep_kernel<<<dim3((WTAP_SZ + 255) / 256), 256, 0, stream>>>(
        w_off, b_off, w_mask, b_mask, wtap, bcat);
    prep_wbf<<<dim3((WBF_SHORTS + 255) / 256), 256, 0, stream>>>(weight, wbf);
    offmask_kernel<<<dim3(2, H, B), 256, 0, stream>>>(x, wtap, bcat, offs, maskb);
    deform2_kernel<<<dim3(2, H, B), 256, 0, stream>>>(x, offs, maskb, wbf, out);
}